// Round 1
// baseline (824.300 us; speedup 1.0000x reference)
//
#include <hip/hip_runtime.h>
#include <math.h>

#define SCAN_B 512

__device__ __forceinline__ float leaky02(float x){ return x > 0.f ? x : 0.2f * x; }
__device__ __forceinline__ float eluf(float x){ return x > 0.f ? x : expm1f(x); }

// ---------------- GEMM1: h1 = x @ W1  (N x 128) @ (128 x 128), fused alpha dots ----
__global__ __launch_bounds__(128) void gemm1_kernel(
    const float* __restrict__ x, const float* __restrict__ W,
    const float* __restrict__ a_src, const float* __restrict__ a_dst, // flat [128]
    float* __restrict__ h, float* __restrict__ as_, float* __restrict__ ad_, int n)
{
  const int t = threadIdx.x;
  const int row0 = blockIdx.x * 8;
  __shared__ float xs[8][128];
  __shared__ float sS[8][128];
  __shared__ float sD[8][128];
  for (int idx = t; idx < 8 * 128; idx += 128) {
    int r = idx >> 7, k = idx & 127;
    xs[r][k] = (row0 + r < n) ? x[(size_t)(row0 + r) * 128 + k] : 0.f;
  }
  __syncthreads();
  double acc[8] = {0,0,0,0,0,0,0,0};
  for (int k = 0; k < 128; ++k) {
    float w = W[k * 128 + t];
    #pragma unroll
    for (int r = 0; r < 8; ++r) acc[r] += (double)xs[r][k] * (double)w;
  }
  float asv = a_src[t], adv = a_dst[t];
  #pragma unroll
  for (int r = 0; r < 8; ++r) {
    float hv = (float)acc[r];
    if (row0 + r < n) h[(size_t)(row0 + r) * 128 + t] = hv;
    sS[r][t] = hv * asv;
    sD[r][t] = hv * adv;
  }
  __syncthreads();
  if (t < 64) {
    int r = t >> 3, head = t & 3, which = (t >> 2) & 1;
    if (row0 + r < n) {
      const float (*buf)[128] = which ? sD : sS;
      double s = 0;
      for (int cc = 0; cc < 32; ++cc) s += (double)buf[r][head * 32 + cc];
      float* dstp = which ? ad_ : as_;
      dstp[(row0 + r) * 4 + head] = (float)s;
    }
  }
}

// ---------------- GEMM2: h2 = act1 @ W2 (N x 128) @ (128 x 32), fused alpha dots ---
__global__ __launch_bounds__(128) void gemm2_kernel(
    const float* __restrict__ x, const float* __restrict__ W,
    const float* __restrict__ a_src, const float* __restrict__ a_dst, // [32]
    float* __restrict__ h, float* __restrict__ as_, float* __restrict__ ad_, int n)
{
  const int t = threadIdx.x;
  const int row0 = blockIdx.x * 8;
  __shared__ float xs[8][128];
  __shared__ float sH[8][32];
  for (int idx = t; idx < 8 * 128; idx += 128) {
    int r = idx >> 7, k = idx & 127;
    xs[r][k] = (row0 + r < n) ? x[(size_t)(row0 + r) * 128 + k] : 0.f;
  }
  __syncthreads();
  int col = t & 31, rp = t >> 5;
  int r0 = rp * 2, r1 = r0 + 1;
  double a0 = 0, a1 = 0;
  for (int k = 0; k < 128; ++k) {
    float w = W[k * 32 + col];
    a0 += (double)xs[r0][k] * (double)w;
    a1 += (double)xs[r1][k] * (double)w;
  }
  float h0 = (float)a0, h1 = (float)a1;
  if (row0 + r0 < n) h[(size_t)(row0 + r0) * 32 + col] = h0;
  if (row0 + r1 < n) h[(size_t)(row0 + r1) * 32 + col] = h1;
  sH[r0][col] = h0; sH[r1][col] = h1;
  __syncthreads();
  if (t < 16) {
    int r = t >> 1, which = t & 1;
    if (row0 + r < n) {
      const float* a = which ? a_dst : a_src;
      double s = 0;
      for (int cc = 0; cc < 32; ++cc) s += (double)sH[r][cc] * (double)a[cc];
      (which ? ad_ : as_)[row0 + r] = (float)s;
    }
  }
}

// ---------------- CSR build ---------------------------------------------------------
__global__ void degree_kernel(const int* __restrict__ dst, int* __restrict__ deg, int E) {
  int e = blockIdx.x * blockDim.x + threadIdx.x;
  if (e < E) atomicAdd(&deg[dst[e]], 1);
}

__global__ __launch_bounds__(SCAN_B) void scan_partial_kernel(
    const int* __restrict__ deg, int* __restrict__ partial, int n)
{
  __shared__ int s[SCAN_B];
  int i = blockIdx.x * SCAN_B + threadIdx.x;
  s[threadIdx.x] = (i < n) ? deg[i] : 0;
  __syncthreads();
  for (int off = SCAN_B / 2; off > 0; off >>= 1) {
    if (threadIdx.x < off) s[threadIdx.x] += s[threadIdx.x + off];
    __syncthreads();
  }
  if (threadIdx.x == 0) partial[blockIdx.x] = s[0];
}

__global__ void scan_offsets_kernel(int* __restrict__ partial, int nb) {
  if (threadIdx.x == 0 && blockIdx.x == 0) {
    int run = 0;
    for (int i = 0; i < nb; ++i) { int v = partial[i]; partial[i] = run; run += v; }
  }
}

__global__ __launch_bounds__(SCAN_B) void scan_final_kernel(
    const int* __restrict__ deg, const int* __restrict__ partial,
    int* __restrict__ rowStart, int n, int Etot)
{
  __shared__ int s[SCAN_B];
  int i = blockIdx.x * SCAN_B + threadIdx.x;
  int v = (i < n) ? deg[i] : 0;
  s[threadIdx.x] = v;
  __syncthreads();
  for (int off = 1; off < SCAN_B; off <<= 1) {
    int xv = (threadIdx.x >= off) ? s[threadIdx.x - off] : 0;
    __syncthreads();
    s[threadIdx.x] += xv;
    __syncthreads();
  }
  if (i < n) rowStart[i] = partial[blockIdx.x] + s[threadIdx.x] - v;  // exclusive scan
  if (i == 0) rowStart[n] = Etot;
}

__global__ void fill_kernel(const int* __restrict__ src, const int* __restrict__ dst,
    const int* __restrict__ rowStart, int* __restrict__ cursor,
    int* __restrict__ col, int E)
{
  int e = blockIdx.x * blockDim.x + threadIdx.x;
  if (e < E) {
    int d = dst[e];
    int pos = rowStart[d] + atomicAdd(&cursor[d], 1);
    col[pos] = src[e];
  }
}

// ---------------- GAT aggregation: one block per destination node -------------------
// CTOT total channels (H*ch), H heads, EPB edges in flight; T = CTOT*EPB threads.
template<int CTOT, int H, int EPB>
__global__ __launch_bounds__(CTOT * EPB) void gat_aggr_kernel(
    const float* __restrict__ feat,   // [n, CTOT]
    const float* __restrict__ as_,    // [n, H]
    const float* __restrict__ ad_,    // [n, H]
    const int* __restrict__ rowStart,
    const int* __restrict__ col,
    const float* __restrict__ bias,   // [CTOT]
    float* __restrict__ out, int n)
{
  constexpr int T = CTOT * EPB;
  constexpr int CHUNK = 64;
  constexpr int CH = CTOT / H;
  const int node = blockIdx.x;
  const int t = threadIdx.x;
  const int beg = rowStart[node];
  const int deg = rowStart[node + 1] - beg;
  const int c   = t % CTOT;
  const int sub = t / CTOT;
  const int hc  = c / CH;
  const int h0  = t & (H - 1);

  __shared__ float  s_redmax[H][T];
  __shared__ float  s_redden[T];
  __shared__ double s_den[H];
  __shared__ int    s_srcb[CHUNK];
  __shared__ float  s_p[CHUNK * H];
  __shared__ double s_racc[T];

  float adv[H];
  #pragma unroll
  for (int h = 0; h < H; ++h) adv[h] = ad_[node * H + h];
  float eself[H];
  #pragma unroll
  for (int h = 0; h < H; ++h) eself[h] = leaky02(as_[node * H + h] + adv[h]);

  // ---- pass 1: per-head max over incoming edges + self ----
  float mloc[H];
  #pragma unroll
  for (int h = 0; h < H; ++h) mloc[h] = eself[h];
  for (int i = t; i < deg; i += T) {
    int s = col[beg + i];
    float av[H];
    if constexpr (H == 4) {
      float4 q = ((const float4*)as_)[s];
      av[0] = q.x; av[1] = q.y; av[2] = q.z; av[3] = q.w;
    } else {
      av[0] = as_[s];
    }
    #pragma unroll
    for (int h = 0; h < H; ++h)
      mloc[h] = fmaxf(mloc[h], leaky02(av[h] + adv[h]));
  }
  #pragma unroll
  for (int h = 0; h < H; ++h) s_redmax[h][t] = mloc[h];
  __syncthreads();
  for (int off = T / 2; off > 0; off >>= 1) {
    if (t < off) {
      #pragma unroll
      for (int h = 0; h < H; ++h)
        s_redmax[h][t] = fmaxf(s_redmax[h][t], s_redmax[h][t + off]);
    }
    __syncthreads();
  }
  const float m_h0 = s_redmax[h0][0];
  const float m_hc = s_redmax[hc][0];

  // ---- self-loop contribution ----
  double accv = 0.0;
  float den_loc = 0.f;
  if (sub == 0) {
    float es_hc = 0.f;
    #pragma unroll
    for (int h = 0; h < H; ++h) if (h == hc) es_hc = eself[h];
    float pself = expf(es_hc - m_hc);
    accv = (double)pself * (double)feat[(size_t)node * CTOT + c];
  }

  // ---- pass 2: exp/sum + weighted accumulate, chunked through LDS ----
  for (int base = 0; base < deg; base += CHUNK) {
    int cnt = min(CHUNK, deg - base);
    for (int i = t; i < cnt; i += T) s_srcb[i] = col[beg + base + i];
    __syncthreads();
    for (int idx = t; idx < cnt * H; idx += T) {
      int e = idx / H;            // H is a power of two
      int s = s_srcb[e];
      float v = leaky02(as_[s * H + h0] + adv[h0]);   // idx&(H-1) == h0 since T%H==0
      float p = expf(v - m_h0);
      s_p[idx] = p;
      den_loc += p;
    }
    __syncthreads();
    for (int j = sub; j < cnt; j += EPB) {
      int s = s_srcb[j];
      float p = s_p[j * H + hc];
      accv += (double)p * (double)feat[(size_t)s * CTOT + c];
    }
    __syncthreads();
  }

  // ---- denominator reduce (+self) ----
  s_redden[t] = den_loc;
  if (EPB > 1) s_racc[t] = accv;
  __syncthreads();
  if (t < H) {
    double d = 0;
    for (int j = t; j < T; j += H) d += (double)s_redden[j];
    float es_t = 0.f;
    #pragma unroll
    for (int h = 0; h < H; ++h) if (h == t) es_t = eself[h];
    d += (double)expf(es_t - s_redmax[t][0]);
    s_den[t] = d;
  }
  __syncthreads();
  if (EPB > 1 && t < CTOT) {
    #pragma unroll
    for (int sb = 1; sb < EPB; ++sb) accv += s_racc[t + sb * CTOT];
  }
  if (t < CTOT) {
    double v = accv / s_den[hc];
    float r = (float)v + bias[c];
    out[(size_t)node * CTOT + c] = eluf(r);
  }
}

// ---------------- pooling + classifier ----------------------------------------------
__global__ void pool_kernel(const float* __restrict__ act2, const int* __restrict__ batch,
    float* __restrict__ pooled, float* __restrict__ cnt, int n)
{
  int idx = blockIdx.x * blockDim.x + threadIdx.x;
  if (idx < n * 32) {
    int i = idx >> 5, c = idx & 31;
    int g = batch[i];
    atomicAdd(&pooled[g * 32 + c], act2[idx]);
    if (c == 0) atomicAdd(&cnt[g], 1.0f);
  }
}

__global__ void classifier_kernel(const float* __restrict__ pooled, const float* __restrict__ cnt,
    const float* __restrict__ Wc1, const float* __restrict__ bc1,
    const float* __restrict__ Wc2, const float* __restrict__ bc2,
    float* __restrict__ outp, int g_total)
{
  int g = blockIdx.x * blockDim.x + threadIdx.x;
  if (g < g_total) {
    float inv = 1.0f / cnt[g];
    float pm[32];
    for (int c = 0; c < 32; ++c) pm[c] = pooled[g * 32 + c] * inv;
    double o = (double)bc2[0];
    for (int j = 0; j < 16; ++j) {
      double z = (double)bc1[j];
      for (int c = 0; c < 32; ++c) z += (double)pm[c] * (double)Wc1[c * 16 + j];
      float zr = (float)z;
      zr = zr > 0.f ? zr : 0.f;
      o += (double)zr * (double)Wc2[j];
    }
    outp[g] = (float)o;
  }
}

// ---------------- launch ------------------------------------------------------------
extern "C" void kernel_launch(void* const* d_in, const int* in_sizes, int n_in,
                              void* d_out, int out_size, void* d_ws, size_t ws_size,
                              hipStream_t stream)
{
  const float* x      = (const float*)d_in[0];
  const int*   ei     = (const int*)d_in[1];
  const int*   batch  = (const int*)d_in[3];
  const float* W1     = (const float*)d_in[4];
  const float* a_src1 = (const float*)d_in[5];
  const float* a_dst1 = (const float*)d_in[6];
  const float* b1     = (const float*)d_in[7];
  const float* W2     = (const float*)d_in[8];
  const float* a_src2 = (const float*)d_in[9];
  const float* a_dst2 = (const float*)d_in[10];
  const float* b2     = (const float*)d_in[11];
  const float* Wc1    = (const float*)d_in[12];
  const float* bc1    = (const float*)d_in[13];
  const float* Wc2    = (const float*)d_in[14];
  const float* bc2    = (const float*)d_in[15];

  const int N = in_sizes[0] / 128;
  const int E = in_sizes[1] / 2;
  const int G = out_size;

  const int* srcv = ei;
  const int* dstv = ei + E;

  char* ws = (char*)d_ws;
  size_t off = 0;
  auto alloc = [&](size_t bytes) -> void* {
    void* p = ws + off;
    off += (bytes + 255) & ~(size_t)255;
    return p;
  };
  float* h1   = (float*)alloc((size_t)N * 128 * 4);
  float* act1 = (float*)alloc((size_t)N * 128 * 4);
  float* h2   = (float*)alloc((size_t)N * 32 * 4);
  float* act2 = (float*)alloc((size_t)N * 32 * 4);
  float* as1  = (float*)alloc((size_t)N * 4 * 4);
  float* ad1  = (float*)alloc((size_t)N * 4 * 4);
  float* as2  = (float*)alloc((size_t)N * 4);
  float* ad2  = (float*)alloc((size_t)N * 4);
  int*   deg      = (int*)alloc((size_t)N * 4);
  int*   cursor   = (int*)alloc((size_t)N * 4);
  int*   rowStart = (int*)alloc((size_t)(N + 1) * 4);
  int*   colv     = (int*)alloc((size_t)E * 4);
  int*   partial  = (int*)alloc(4096);
  float* pooled   = (float*)alloc((size_t)G * 32 * 4);
  float* cntG     = (float*)alloc((size_t)G * 4);

  hipMemsetAsync(deg,    0, (size_t)N * 4, stream);
  hipMemsetAsync(cursor, 0, (size_t)N * 4, stream);
  hipMemsetAsync(pooled, 0, (size_t)G * 32 * 4, stream);
  hipMemsetAsync(cntG,   0, (size_t)G * 4, stream);

  // CSR by destination
  int eb = (E + 255) / 256;
  int nb = (N + SCAN_B - 1) / SCAN_B;
  degree_kernel<<<eb, 256, 0, stream>>>(dstv, deg, E);
  scan_partial_kernel<<<nb, SCAN_B, 0, stream>>>(deg, partial, N);
  scan_offsets_kernel<<<1, 1, 0, stream>>>(partial, nb);
  scan_final_kernel<<<nb, SCAN_B, 0, stream>>>(deg, partial, rowStart, N, E);
  fill_kernel<<<eb, 256, 0, stream>>>(srcv, dstv, rowStart, cursor, colv, E);

  // layer 1
  gemm1_kernel<<<(N + 7) / 8, 128, 0, stream>>>(x, W1, a_src1, a_dst1, h1, as1, ad1, N);
  gat_aggr_kernel<128, 4, 1><<<N, 128, 0, stream>>>(h1, as1, ad1, rowStart, colv, b1, act1, N);

  // layer 2
  gemm2_kernel<<<(N + 7) / 8, 128, 0, stream>>>(act1, W2, a_src2, a_dst2, h2, as2, ad2, N);
  gat_aggr_kernel<32, 1, 2><<<N, 64, 0, stream>>>(h2, as2, ad2, rowStart, colv, b2, act2, N);

  // pool + classify
  int pb = (N * 32 + 255) / 256;
  pool_kernel<<<pb, 256, 0, stream>>>(act2, batch, pooled, cntG, N);
  classifier_kernel<<<(G + 255) / 256, 256, 0, stream>>>(pooled, cntG, Wc1, bc1, Wc2, bc2,
                                                         (float*)d_out, G);
}

// Round 2
// 566.854 us; speedup vs baseline: 1.4542x; 1.4542x over previous
//
#include <hip/hip_runtime.h>
#include <math.h>

#define SCAN_B 512

__device__ __forceinline__ float leaky02(float x){ return x > 0.f ? x : 0.2f * x; }
__device__ __forceinline__ float eluf(float x){ return x > 0.f ? x : expm1f(x); }

// ---------------- GEMM1: h1 = x @ W1  (N x 128) @ (128 x 128), fused alpha dots ----
__global__ __launch_bounds__(128) void gemm1_kernel(
    const float* __restrict__ x, const float* __restrict__ W,
    const float* __restrict__ a_src, const float* __restrict__ a_dst, // flat [128]
    float* __restrict__ h, float* __restrict__ as_, float* __restrict__ ad_, int n)
{
  const int t = threadIdx.x;
  const int row0 = blockIdx.x * 8;
  __shared__ float xs[8][128];
  __shared__ float sS[8][128];
  __shared__ float sD[8][128];
  for (int idx = t; idx < 8 * 128; idx += 128) {
    int r = idx >> 7, k = idx & 127;
    xs[r][k] = (row0 + r < n) ? x[(size_t)(row0 + r) * 128 + k] : 0.f;
  }
  __syncthreads();
  double acc[8] = {0,0,0,0,0,0,0,0};
  for (int k = 0; k < 128; ++k) {
    float w = W[k * 128 + t];
    #pragma unroll
    for (int r = 0; r < 8; ++r) acc[r] += (double)xs[r][k] * (double)w;
  }
  float asv = a_src[t], adv = a_dst[t];
  #pragma unroll
  for (int r = 0; r < 8; ++r) {
    float hv = (float)acc[r];
    if (row0 + r < n) h[(size_t)(row0 + r) * 128 + t] = hv;
    sS[r][t] = hv * asv;
    sD[r][t] = hv * adv;
  }
  __syncthreads();
  if (t < 64) {
    int r = t >> 3, head = t & 3, which = (t >> 2) & 1;
    if (row0 + r < n) {
      const float (*buf)[128] = which ? sD : sS;
      double s = 0;
      for (int cc = 0; cc < 32; ++cc) s += (double)buf[r][head * 32 + cc];
      float* dstp = which ? ad_ : as_;
      dstp[(row0 + r) * 4 + head] = (float)s;
    }
  }
}

// ---------------- GEMM2: h2 = act1 @ W2 (N x 128) @ (128 x 32), fused alpha dots ---
__global__ __launch_bounds__(128) void gemm2_kernel(
    const float* __restrict__ x, const float* __restrict__ W,
    const float* __restrict__ a_src, const float* __restrict__ a_dst, // [32]
    float* __restrict__ h, float* __restrict__ as_, float* __restrict__ ad_, int n)
{
  const int t = threadIdx.x;
  const int row0 = blockIdx.x * 8;
  __shared__ float xs[8][128];
  __shared__ float sH[8][32];
  for (int idx = t; idx < 8 * 128; idx += 128) {
    int r = idx >> 7, k = idx & 127;
    xs[r][k] = (row0 + r < n) ? x[(size_t)(row0 + r) * 128 + k] : 0.f;
  }
  __syncthreads();
  int col = t & 31, rp = t >> 5;
  int r0 = rp * 2, r1 = r0 + 1;
  double a0 = 0, a1 = 0;
  for (int k = 0; k < 128; ++k) {
    float w = W[k * 32 + col];
    a0 += (double)xs[r0][k] * (double)w;
    a1 += (double)xs[r1][k] * (double)w;
  }
  float h0 = (float)a0, h1 = (float)a1;
  if (row0 + r0 < n) h[(size_t)(row0 + r0) * 32 + col] = h0;
  if (row0 + r1 < n) h[(size_t)(row0 + r1) * 32 + col] = h1;
  sH[r0][col] = h0; sH[r1][col] = h1;
  __syncthreads();
  if (t < 16) {
    int r = t >> 1, which = t & 1;
    if (row0 + r < n) {
      const float* a = which ? a_dst : a_src;
      double s = 0;
      for (int cc = 0; cc < 32; ++cc) s += (double)sH[r][cc] * (double)a[cc];
      (which ? ad_ : as_)[row0 + r] = (float)s;
    }
  }
}

// ---------------- CSR build ---------------------------------------------------------
__global__ void degree_kernel(const int* __restrict__ dst, int* __restrict__ deg, int E) {
  int e = blockIdx.x * blockDim.x + threadIdx.x;
  if (e < E) atomicAdd(&deg[dst[e]], 1);
}

__global__ __launch_bounds__(SCAN_B) void scan_partial_kernel(
    const int* __restrict__ deg, int* __restrict__ partial, int n)
{
  __shared__ int s[SCAN_B];
  int i = blockIdx.x * SCAN_B + threadIdx.x;
  s[threadIdx.x] = (i < n) ? deg[i] : 0;
  __syncthreads();
  for (int off = SCAN_B / 2; off > 0; off >>= 1) {
    if (threadIdx.x < off) s[threadIdx.x] += s[threadIdx.x + off];
    __syncthreads();
  }
  if (threadIdx.x == 0) partial[blockIdx.x] = s[0];
}

// single-block parallel exclusive scan over the per-block partials
__global__ __launch_bounds__(256) void scan_offsets_kernel(int* __restrict__ partial, int nb) {
  __shared__ int s[256];
  __shared__ int carry_s;
  int t = threadIdx.x;
  if (t == 0) carry_s = 0;
  __syncthreads();
  for (int b = 0; b < nb; b += 256) {
    int v = (b + t < nb) ? partial[b + t] : 0;
    s[t] = v;
    __syncthreads();
    for (int off = 1; off < 256; off <<= 1) {
      int x = (t >= off) ? s[t - off] : 0;
      __syncthreads();
      s[t] += x;
      __syncthreads();
    }
    int incl = s[t];
    int carry = carry_s;
    if (b + t < nb) partial[b + t] = carry + incl - v;   // exclusive
    __syncthreads();
    if (t == 255) carry_s = carry + incl;
    __syncthreads();
  }
}

__global__ __launch_bounds__(SCAN_B) void scan_final_kernel(
    const int* __restrict__ deg, const int* __restrict__ partial,
    int* __restrict__ rowStart, int n, int Etot)
{
  __shared__ int s[SCAN_B];
  int i = blockIdx.x * SCAN_B + threadIdx.x;
  int v = (i < n) ? deg[i] : 0;
  s[threadIdx.x] = v;
  __syncthreads();
  for (int off = 1; off < SCAN_B; off <<= 1) {
    int xv = (threadIdx.x >= off) ? s[threadIdx.x - off] : 0;
    __syncthreads();
    s[threadIdx.x] += xv;
    __syncthreads();
  }
  if (i < n) rowStart[i] = partial[blockIdx.x] + s[threadIdx.x] - v;  // exclusive scan
  if (i == 0) rowStart[n] = Etot;
}

__global__ void fill_kernel(const int* __restrict__ src, const int* __restrict__ dst,
    const int* __restrict__ rowStart, int* __restrict__ cursor,
    int* __restrict__ col, int E)
{
  int e = blockIdx.x * blockDim.x + threadIdx.x;
  if (e < E) {
    int d = dst[e];
    int pos = rowStart[d] + atomicAdd(&cursor[d], 1);
    col[pos] = src[e];
  }
}

// ---------------- GAT aggregation v2: one block per destination node ----------------
// No max pass (softmax is shift-invariant; e bounded). float4 per lane.
// CTOT channels, H heads, T threads. L = CTOT/4 lanes per edge row, GR = T/L groups.
template<int CTOT, int H, int T>
__global__ __launch_bounds__(T) void gat_aggr2_kernel(
    const float* __restrict__ feat,   // [n, CTOT]
    const float* __restrict__ as_,    // [n, H]
    const float* __restrict__ ad_,    // [n, H]
    const int* __restrict__ rowStart,
    const int* __restrict__ col,
    const float* __restrict__ bias,   // [CTOT]
    float* __restrict__ out, int n)
{
  constexpr int L  = CTOT / 4;   // lanes covering one feature row
  constexpr int GR = T / L;      // edge rows in flight
  constexpr int CH = CTOT / H;   // channels per head
  constexpr int CHUNK = T;
  const int node = blockIdx.x;
  const int t = threadIdx.x;
  const int l = t % L;
  const int g = t / L;
  const int hc = (4 * l) / CH;   // head owning this lane's 4 channels

  const int beg = rowStart[node];
  const int deg = rowStart[node + 1] - beg;

  __shared__ int    s_off[CHUNK];
  __shared__ float  s_p[CHUNK * H];
  __shared__ double s_racc[T][5];  // padded stride
  __shared__ double s_dred[T];

  float adv[H], eself[H];
  #pragma unroll
  for (int h = 0; h < H; ++h) adv[h] = ad_[node * H + h];
  #pragma unroll
  for (int h = 0; h < H; ++h) eself[h] = leaky02(as_[node * H + h] + adv[h]);

  double acc64[4] = {0, 0, 0, 0};
  double den64 = 0.0;

  // self-loop contribution (group 0 only)
  if (g == 0) {
    float es = 0.f;
    #pragma unroll
    for (int h = 0; h < H; ++h) if (h == hc) es = eself[h];
    float ps = expf(es);
    const float4 f = *(const float4*)(feat + (size_t)node * CTOT + 4 * l);
    acc64[0] = (double)ps * (double)f.x;
    acc64[1] = (double)ps * (double)f.y;
    acc64[2] = (double)ps * (double)f.z;
    acc64[3] = (double)ps * (double)f.w;
  }

  for (int base = 0; base < deg; base += CHUNK) {
    int cnt = min(CHUNK, deg - base);
    if (t < cnt) {
      int s = col[beg + base + t];
      s_off[t] = s * CTOT;
      if constexpr (H == 4) {
        float4 q = ((const float4*)as_)[s];
        s_p[t * 4 + 0] = expf(leaky02(q.x + adv[0]));
        s_p[t * 4 + 1] = expf(leaky02(q.y + adv[1]));
        s_p[t * 4 + 2] = expf(leaky02(q.z + adv[2]));
        s_p[t * 4 + 3] = expf(leaky02(q.w + adv[3]));
      } else {
        s_p[t] = expf(leaky02(as_[s] + adv[0]));
      }
    }
    __syncthreads();
    float a0 = 0.f, a1 = 0.f, a2 = 0.f, a3 = 0.f, df = 0.f;
    #pragma unroll 2
    for (int j = g; j < cnt; j += GR) {
      int off = s_off[j];
      float p = s_p[j * H + hc];
      const float4 f = *(const float4*)(feat + off + 4 * l);
      a0 += p * f.x; a1 += p * f.y; a2 += p * f.z; a3 += p * f.w;
      df += p;
    }
    acc64[0] += a0; acc64[1] += a1; acc64[2] += a2; acc64[3] += a3;
    den64 += df;
    __syncthreads();
  }

  s_racc[t][0] = acc64[0]; s_racc[t][1] = acc64[1];
  s_racc[t][2] = acc64[2]; s_racc[t][3] = acc64[3];
  s_dred[t] = den64;
  __syncthreads();

  if (t < L) {
    const int hh = (4 * t) / CH;
    double tot[4] = {0, 0, 0, 0};
    #pragma unroll
    for (int gg = 0; gg < GR; ++gg) {
      #pragma unroll
      for (int i = 0; i < 4; ++i) tot[i] += s_racc[t + gg * L][i];
    }
    float es = 0.f;
    #pragma unroll
    for (int h = 0; h < H; ++h) if (h == hh) es = eself[h];
    double den = (double)expf(es);
    #pragma unroll
    for (int gg = 0; gg < GR; ++gg) den += s_dred[gg * L + hh * (L / H)];
    const float4 bv = *(const float4*)(bias + 4 * t);
    float4 o;
    o.x = eluf((float)(tot[0] / den) + bv.x);
    o.y = eluf((float)(tot[1] / den) + bv.y);
    o.z = eluf((float)(tot[2] / den) + bv.z);
    o.w = eluf((float)(tot[3] / den) + bv.w);
    *(float4*)(out + (size_t)node * CTOT + 4 * t) = o;
  }
}

// ---------------- pooling (batch is sorted: run-length flush) -----------------------
__global__ __launch_bounds__(256) void pool_kernel(const float* __restrict__ act2,
    const int* __restrict__ batch, float* __restrict__ pooled,
    float* __restrict__ cnt, int n)
{
  int t = threadIdx.x;
  int c = t & 31, r = t >> 5;
  int n0 = blockIdx.x * 64 + r * 8;
  float run = 0.f; int gcur = -1; int len = 0;
  for (int i = 0; i < 8; ++i) {
    int nd = n0 + i;
    if (nd >= n) break;
    int gb = batch[nd];
    if (gb != gcur) {
      if (gcur >= 0) {
        atomicAdd(&pooled[gcur * 32 + c], run);
        if (c == 0) atomicAdd(&cnt[gcur], (float)len);
      }
      gcur = gb; run = 0.f; len = 0;
    }
    run += act2[(size_t)nd * 32 + c];
    len++;
  }
  if (gcur >= 0) {
    atomicAdd(&pooled[gcur * 32 + c], run);
    if (c == 0) atomicAdd(&cnt[gcur], (float)len);
  }
}

__global__ void classifier_kernel(const float* __restrict__ pooled, const float* __restrict__ cnt,
    const float* __restrict__ Wc1, const float* __restrict__ bc1,
    const float* __restrict__ Wc2, const float* __restrict__ bc2,
    float* __restrict__ outp, int g_total)
{
  int g = blockIdx.x * blockDim.x + threadIdx.x;
  if (g < g_total) {
    float inv = 1.0f / cnt[g];
    float pm[32];
    for (int c = 0; c < 32; ++c) pm[c] = pooled[g * 32 + c] * inv;
    double o = (double)bc2[0];
    for (int j = 0; j < 16; ++j) {
      double z = (double)bc1[j];
      for (int c = 0; c < 32; ++c) z += (double)pm[c] * (double)Wc1[c * 16 + j];
      float zr = (float)z;
      zr = zr > 0.f ? zr : 0.f;
      o += (double)zr * (double)Wc2[j];
    }
    outp[g] = (float)o;
  }
}

// ---------------- launch ------------------------------------------------------------
extern "C" void kernel_launch(void* const* d_in, const int* in_sizes, int n_in,
                              void* d_out, int out_size, void* d_ws, size_t ws_size,
                              hipStream_t stream)
{
  const float* x      = (const float*)d_in[0];
  const int*   ei     = (const int*)d_in[1];
  const int*   batch  = (const int*)d_in[3];
  const float* W1     = (const float*)d_in[4];
  const float* a_src1 = (const float*)d_in[5];
  const float* a_dst1 = (const float*)d_in[6];
  const float* b1     = (const float*)d_in[7];
  const float* W2     = (const float*)d_in[8];
  const float* a_src2 = (const float*)d_in[9];
  const float* a_dst2 = (const float*)d_in[10];
  const float* b2     = (const float*)d_in[11];
  const float* Wc1    = (const float*)d_in[12];
  const float* bc1    = (const float*)d_in[13];
  const float* Wc2    = (const float*)d_in[14];
  const float* bc2    = (const float*)d_in[15];

  const int N = in_sizes[0] / 128;
  const int E = in_sizes[1] / 2;
  const int G = out_size;

  const int* srcv = ei;
  const int* dstv = ei + E;

  char* ws = (char*)d_ws;
  size_t off = 0;
  auto alloc = [&](size_t bytes) -> void* {
    void* p = ws + off;
    off += (bytes + 255) & ~(size_t)255;
    return p;
  };
  float* h1   = (float*)alloc((size_t)N * 128 * 4);
  float* act1 = (float*)alloc((size_t)N * 128 * 4);
  float* h2   = (float*)alloc((size_t)N * 32 * 4);
  float* act2 = (float*)alloc((size_t)N * 32 * 4);
  float* as1  = (float*)alloc((size_t)N * 4 * 4);
  float* ad1  = (float*)alloc((size_t)N * 4 * 4);
  float* as2  = (float*)alloc((size_t)N * 4);
  float* ad2  = (float*)alloc((size_t)N * 4);
  int*   deg      = (int*)alloc((size_t)N * 4);
  int*   cursor   = (int*)alloc((size_t)N * 4);
  int*   rowStart = (int*)alloc((size_t)(N + 1) * 4);
  int*   colv     = (int*)alloc((size_t)E * 4);
  int*   partial  = (int*)alloc(4096);
  float* pooled   = (float*)alloc((size_t)G * 32 * 4);
  float* cntG     = (float*)alloc((size_t)G * 4);

  hipMemsetAsync(deg,    0, (size_t)N * 4, stream);
  hipMemsetAsync(cursor, 0, (size_t)N * 4, stream);
  hipMemsetAsync(pooled, 0, (size_t)G * 32 * 4, stream);
  hipMemsetAsync(cntG,   0, (size_t)G * 4, stream);

  // CSR by destination
  int eb = (E + 255) / 256;
  int nb = (N + SCAN_B - 1) / SCAN_B;
  degree_kernel<<<eb, 256, 0, stream>>>(dstv, deg, E);
  scan_partial_kernel<<<nb, SCAN_B, 0, stream>>>(deg, partial, N);
  scan_offsets_kernel<<<1, 256, 0, stream>>>(partial, nb);
  scan_final_kernel<<<nb, SCAN_B, 0, stream>>>(deg, partial, rowStart, N, E);
  fill_kernel<<<eb, 256, 0, stream>>>(srcv, dstv, rowStart, cursor, colv, E);

  // layer 1
  gemm1_kernel<<<(N + 7) / 8, 128, 0, stream>>>(x, W1, a_src1, a_dst1, h1, as1, ad1, N);
  gat_aggr2_kernel<128, 4, 128><<<N, 128, 0, stream>>>(h1, as1, ad1, rowStart, colv, b1, act1, N);

  // layer 2
  gemm2_kernel<<<(N + 7) / 8, 128, 0, stream>>>(act1, W2, a_src2, a_dst2, h2, as2, ad2, N);
  gat_aggr2_kernel<32, 1, 64><<<N, 64, 0, stream>>>(h2, as2, ad2, rowStart, colv, b2, act2, N);

  // pool + classify
  pool_kernel<<<(N + 63) / 64, 256, 0, stream>>>(act2, batch, pooled, cntG, N);
  classifier_kernel<<<(G + 255) / 256, 256, 0, stream>>>(pooled, cntG, Wc1, bc1, Wc2, bc2,
                                                         (float*)d_out, G);
}

// Round 3
// 536.756 us; speedup vs baseline: 1.5357x; 1.0561x over previous
//
#include <hip/hip_runtime.h>
#include <math.h>

#define SCAN_B 512

__device__ __forceinline__ float leaky02(float x){ return x > 0.f ? x : 0.2f * x; }
__device__ __forceinline__ float eluf(float x){ return x > 0.f ? x : expm1f(x); }

// ---------------- GEMM1: h1 = x @ W1  (N x 128) @ (128 x 128), fused alpha dots ----
__global__ __launch_bounds__(128) void gemm1_kernel(
    const float* __restrict__ x, const float* __restrict__ W,
    const float* __restrict__ a_src, const float* __restrict__ a_dst, // flat [128]
    float* __restrict__ h, float* __restrict__ as_, float* __restrict__ ad_, int n)
{
  const int t = threadIdx.x;
  const int row0 = blockIdx.x * 8;
  __shared__ float xs[8][128];
  __shared__ float sS[8][128];
  __shared__ float sD[8][128];
  for (int idx = t; idx < 8 * 32; idx += 128) {
    int r = idx >> 5, k4 = idx & 31;
    float4 v = (row0 + r < n) ? ((const float4*)x)[(size_t)(row0 + r) * 32 + k4]
                              : make_float4(0.f, 0.f, 0.f, 0.f);
    *(float4*)&xs[r][k4 * 4] = v;
  }
  __syncthreads();
  float acc[8] = {0,0,0,0,0,0,0,0};
  for (int k = 0; k < 128; ++k) {
    float w = W[k * 128 + t];
    #pragma unroll
    for (int r = 0; r < 8; ++r) acc[r] += xs[r][k] * w;
  }
  float asv = a_src[t], adv = a_dst[t];
  #pragma unroll
  for (int r = 0; r < 8; ++r) {
    float hv = acc[r];
    if (row0 + r < n) h[(size_t)(row0 + r) * 128 + t] = hv;
    sS[r][t] = hv * asv;
    sD[r][t] = hv * adv;
  }
  __syncthreads();
  if (t < 64) {
    int r = t >> 3, head = t & 3, which = (t >> 2) & 1;
    if (row0 + r < n) {
      const float (*buf)[128] = which ? sD : sS;
      double s = 0;
      for (int cc = 0; cc < 32; ++cc) s += (double)buf[r][head * 32 + cc];
      float* dstp = which ? ad_ : as_;
      dstp[(row0 + r) * 4 + head] = (float)s;
    }
  }
}

// ---------------- GEMM2: h2 = act1 @ W2 (N x 128) @ (128 x 32), fused alpha dots ---
__global__ __launch_bounds__(128) void gemm2_kernel(
    const float* __restrict__ x, const float* __restrict__ W,
    const float* __restrict__ a_src, const float* __restrict__ a_dst, // [32]
    float* __restrict__ h, float* __restrict__ as_, float* __restrict__ ad_, int n)
{
  const int t = threadIdx.x;
  const int row0 = blockIdx.x * 8;
  __shared__ float xs[8][128];
  __shared__ float sH[8][32];
  for (int idx = t; idx < 8 * 32; idx += 128) {
    int r = idx >> 5, k4 = idx & 31;
    float4 v = (row0 + r < n) ? ((const float4*)x)[(size_t)(row0 + r) * 32 + k4]
                              : make_float4(0.f, 0.f, 0.f, 0.f);
    *(float4*)&xs[r][k4 * 4] = v;
  }
  __syncthreads();
  int col = t & 31, rp = t >> 5;
  int r0 = rp * 2, r1 = r0 + 1;
  float a0 = 0, a1 = 0;
  for (int k = 0; k < 128; ++k) {
    float w = W[k * 32 + col];
    a0 += xs[r0][k] * w;
    a1 += xs[r1][k] * w;
  }
  if (row0 + r0 < n) h[(size_t)(row0 + r0) * 32 + col] = a0;
  if (row0 + r1 < n) h[(size_t)(row0 + r1) * 32 + col] = a1;
  sH[r0][col] = a0; sH[r1][col] = a1;
  __syncthreads();
  if (t < 16) {
    int r = t >> 1, which = t & 1;
    if (row0 + r < n) {
      const float* a = which ? a_dst : a_src;
      double s = 0;
      for (int cc = 0; cc < 32; ++cc) s += (double)sH[r][cc] * (double)a[cc];
      (which ? ad_ : as_)[row0 + r] = (float)s;
    }
  }
}

// ---------------- CSR build ---------------------------------------------------------
__global__ void degree_kernel(const int* __restrict__ dst, int* __restrict__ deg, int E) {
  int e = blockIdx.x * blockDim.x + threadIdx.x;
  if (e < E) atomicAdd(&deg[dst[e]], 1);
}

__global__ __launch_bounds__(SCAN_B) void scan_partial_kernel(
    const int* __restrict__ deg, int* __restrict__ partial, int n)
{
  __shared__ int s[SCAN_B];
  int i = blockIdx.x * SCAN_B + threadIdx.x;
  s[threadIdx.x] = (i < n) ? deg[i] : 0;
  __syncthreads();
  for (int off = SCAN_B / 2; off > 0; off >>= 1) {
    if (threadIdx.x < off) s[threadIdx.x] += s[threadIdx.x + off];
    __syncthreads();
  }
  if (threadIdx.x == 0) partial[blockIdx.x] = s[0];
}

// single-block parallel exclusive scan over the per-block partials
__global__ __launch_bounds__(256) void scan_offsets_kernel(int* __restrict__ partial, int nb) {
  __shared__ int s[256];
  __shared__ int carry_s;
  int t = threadIdx.x;
  if (t == 0) carry_s = 0;
  __syncthreads();
  for (int b = 0; b < nb; b += 256) {
    int v = (b + t < nb) ? partial[b + t] : 0;
    s[t] = v;
    __syncthreads();
    for (int off = 1; off < 256; off <<= 1) {
      int x = (t >= off) ? s[t - off] : 0;
      __syncthreads();
      s[t] += x;
      __syncthreads();
    }
    int incl = s[t];
    int carry = carry_s;
    if (b + t < nb) partial[b + t] = carry + incl - v;   // exclusive
    __syncthreads();
    if (t == 255) carry_s = carry + incl;
    __syncthreads();
  }
}

__global__ __launch_bounds__(SCAN_B) void scan_final_kernel(
    const int* __restrict__ deg, const int* __restrict__ partial,
    int* __restrict__ rowStart, int n, int Etot)
{
  __shared__ int s[SCAN_B];
  int i = blockIdx.x * SCAN_B + threadIdx.x;
  int v = (i < n) ? deg[i] : 0;
  s[threadIdx.x] = v;
  __syncthreads();
  for (int off = 1; off < SCAN_B; off <<= 1) {
    int xv = (threadIdx.x >= off) ? s[threadIdx.x - off] : 0;
    __syncthreads();
    s[threadIdx.x] += xv;
    __syncthreads();
  }
  if (i < n) rowStart[i] = partial[blockIdx.x] + s[threadIdx.x] - v;  // exclusive scan
  if (i == 0) rowStart[n] = Etot;
}

__global__ void fill_kernel(const int* __restrict__ src, const int* __restrict__ dst,
    const int* __restrict__ rowStart, int* __restrict__ cursor,
    int* __restrict__ col, int E)
{
  int e = blockIdx.x * blockDim.x + threadIdx.x;
  if (e < E) {
    int d = dst[e];
    int pos = rowStart[d] + atomicAdd(&cursor[d], 1);
    col[pos] = src[e];
  }
}

// ---------------- GAT aggregation v3: wave-private, barrier-free --------------------
// Each node owned by L = CTOT/4 lanes of one wave. Staging in wave-private LDS
// (no __syncthreads). Every lane accumulates the full denominator for its head.
template<int CTOT, int H>
__global__ __launch_bounds__(256) void gat_aggr3_kernel(
    const float* __restrict__ feat,   // [n, CTOT]
    const float* __restrict__ as_,    // [n, H]
    const float* __restrict__ ad_,    // [n, H]
    const int* __restrict__ rowStart,
    const int* __restrict__ col,
    const float* __restrict__ bias,   // [CTOT]
    float* __restrict__ out, int n)
{
  constexpr int L    = CTOT / 4;   // lanes per node
  constexpr int NPW  = 64 / L;     // nodes per wave
  constexpr int NPB  = 4 * NPW;    // nodes per block (256 thr = 4 waves)
  constexpr int CH   = CTOT / H;   // channels per head
  constexpr int CHUNK = L;         // edges staged per round

  const int t    = threadIdx.x;
  const int wave = t >> 6;
  const int lane = t & 63;
  const int grp  = lane / L;
  const int li   = lane % L;
  const int slot = wave * NPW + grp;
  const int node = blockIdx.x * NPB + slot;
  const int hc   = (4 * li) / CH;

  __shared__ int   s_off[NPB][CHUNK + 1];
  __shared__ float s_p[NPB][CHUNK * H + 1];

  if (node >= n) return;   // safe: no barriers below

  const int beg = rowStart[node];
  const int deg = rowStart[node + 1] - beg;

  float adv[H], eself[H];
  #pragma unroll
  for (int h = 0; h < H; ++h) adv[h] = ad_[node * H + h];
  #pragma unroll
  for (int h = 0; h < H; ++h) eself[h] = leaky02(as_[node * H + h] + adv[h]);

  float es = 0.f;
  #pragma unroll
  for (int h = 0; h < H; ++h) if (h == hc) es = eself[h];
  const float ps = expf(es);

  const float4 fself = *(const float4*)(feat + (size_t)node * CTOT + 4 * li);
  double acc64[4];
  acc64[0] = (double)ps * (double)fself.x;
  acc64[1] = (double)ps * (double)fself.y;
  acc64[2] = (double)ps * (double)fself.z;
  acc64[3] = (double)ps * (double)fself.w;
  double den64 = (double)ps;

  for (int base = 0; base < deg; base += CHUNK) {
    const int cnt = min(CHUNK, deg - base);
    if (li < cnt) {
      int s = col[beg + base + li];
      s_off[slot][li] = s * CTOT;
      if constexpr (H == 4) {
        float4 q = ((const float4*)as_)[s];
        s_p[slot][li * 4 + 0] = expf(leaky02(q.x + adv[0]));
        s_p[slot][li * 4 + 1] = expf(leaky02(q.y + adv[1]));
        s_p[slot][li * 4 + 2] = expf(leaky02(q.z + adv[2]));
        s_p[slot][li * 4 + 3] = expf(leaky02(q.w + adv[3]));
      } else {
        s_p[slot][li] = expf(leaky02(as_[s] + adv[0]));
      }
    }
    __builtin_amdgcn_wave_barrier();   // keep staging before consumption
    float a0 = 0.f, a1 = 0.f, a2 = 0.f, a3 = 0.f, df = 0.f;
    #pragma unroll 4
    for (int j = 0; j < cnt; ++j) {
      int off = s_off[slot][j];
      float p = (H == 4) ? s_p[slot][j * 4 + hc] : s_p[slot][j];
      const float4 f = *(const float4*)(feat + off + 4 * li);
      a0 += p * f.x; a1 += p * f.y; a2 += p * f.z; a3 += p * f.w;
      df += p;
    }
    __builtin_amdgcn_wave_barrier();   // keep consumption before next staging
    acc64[0] += a0; acc64[1] += a1; acc64[2] += a2; acc64[3] += a3;
    den64 += df;
  }

  const float4 bv = *(const float4*)(bias + 4 * li);
  float4 o;
  o.x = eluf((float)(acc64[0] / den64) + bv.x);
  o.y = eluf((float)(acc64[1] / den64) + bv.y);
  o.z = eluf((float)(acc64[2] / den64) + bv.z);
  o.w = eluf((float)(acc64[3] / den64) + bv.w);
  *(float4*)(out + (size_t)node * CTOT + 4 * li) = o;
}

// ---------------- pooling (batch is sorted: run-length flush) -----------------------
__global__ __launch_bounds__(256) void pool_kernel(const float* __restrict__ act2,
    const int* __restrict__ batch, float* __restrict__ pooled,
    float* __restrict__ cnt, int n)
{
  int t = threadIdx.x;
  int c = t & 31, r = t >> 5;
  int n0 = blockIdx.x * 64 + r * 8;
  float run = 0.f; int gcur = -1; int len = 0;
  for (int i = 0; i < 8; ++i) {
    int nd = n0 + i;
    if (nd >= n) break;
    int gb = batch[nd];
    if (gb != gcur) {
      if (gcur >= 0) {
        atomicAdd(&pooled[gcur * 32 + c], run);
        if (c == 0) atomicAdd(&cnt[gcur], (float)len);
      }
      gcur = gb; run = 0.f; len = 0;
    }
    run += act2[(size_t)nd * 32 + c];
    len++;
  }
  if (gcur >= 0) {
    atomicAdd(&pooled[gcur * 32 + c], run);
    if (c == 0) atomicAdd(&cnt[gcur], (float)len);
  }
}

__global__ void classifier_kernel(const float* __restrict__ pooled, const float* __restrict__ cnt,
    const float* __restrict__ Wc1, const float* __restrict__ bc1,
    const float* __restrict__ Wc2, const float* __restrict__ bc2,
    float* __restrict__ outp, int g_total)
{
  int g = blockIdx.x * blockDim.x + threadIdx.x;
  if (g < g_total) {
    float inv = 1.0f / cnt[g];
    float pm[32];
    for (int c = 0; c < 32; ++c) pm[c] = pooled[g * 32 + c] * inv;
    double o = (double)bc2[0];
    for (int j = 0; j < 16; ++j) {
      double z = (double)bc1[j];
      for (int c = 0; c < 32; ++c) z += (double)pm[c] * (double)Wc1[c * 16 + j];
      float zr = (float)z;
      zr = zr > 0.f ? zr : 0.f;
      o += (double)zr * (double)Wc2[j];
    }
    outp[g] = (float)o;
  }
}

// ---------------- launch ------------------------------------------------------------
extern "C" void kernel_launch(void* const* d_in, const int* in_sizes, int n_in,
                              void* d_out, int out_size, void* d_ws, size_t ws_size,
                              hipStream_t stream)
{
  const float* x      = (const float*)d_in[0];
  const int*   ei     = (const int*)d_in[1];
  const int*   batch  = (const int*)d_in[3];
  const float* W1     = (const float*)d_in[4];
  const float* a_src1 = (const float*)d_in[5];
  const float* a_dst1 = (const float*)d_in[6];
  const float* b1     = (const float*)d_in[7];
  const float* W2     = (const float*)d_in[8];
  const float* a_src2 = (const float*)d_in[9];
  const float* a_dst2 = (const float*)d_in[10];
  const float* b2     = (const float*)d_in[11];
  const float* Wc1    = (const float*)d_in[12];
  const float* bc1    = (const float*)d_in[13];
  const float* Wc2    = (const float*)d_in[14];
  const float* bc2    = (const float*)d_in[15];

  const int N = in_sizes[0] / 128;
  const int E = in_sizes[1] / 2;
  const int G = out_size;

  const int* srcv = ei;
  const int* dstv = ei + E;

  char* ws = (char*)d_ws;
  size_t off = 0;
  auto alloc = [&](size_t bytes) -> void* {
    void* p = ws + off;
    off += (bytes + 255) & ~(size_t)255;
    return p;
  };
  float* h1   = (float*)alloc((size_t)N * 128 * 4);
  float* act1 = (float*)alloc((size_t)N * 128 * 4);
  float* h2   = (float*)alloc((size_t)N * 32 * 4);
  float* act2 = (float*)alloc((size_t)N * 32 * 4);
  float* as1  = (float*)alloc((size_t)N * 4 * 4);
  float* ad1  = (float*)alloc((size_t)N * 4 * 4);
  float* as2  = (float*)alloc((size_t)N * 4);
  float* ad2  = (float*)alloc((size_t)N * 4);
  int*   deg      = (int*)alloc((size_t)N * 4);
  int*   cursor   = (int*)alloc((size_t)N * 4);
  int*   rowStart = (int*)alloc((size_t)(N + 1) * 4);
  int*   colv     = (int*)alloc((size_t)E * 4);
  int*   partial  = (int*)alloc(4096);
  float* pooled   = (float*)alloc((size_t)G * 32 * 4);
  float* cntG     = (float*)alloc((size_t)G * 4);

  hipMemsetAsync(deg,    0, (size_t)N * 4, stream);
  hipMemsetAsync(cursor, 0, (size_t)N * 4, stream);
  hipMemsetAsync(pooled, 0, (size_t)G * 32 * 4, stream);
  hipMemsetAsync(cntG,   0, (size_t)G * 4, stream);

  // CSR by destination
  int eb = (E + 255) / 256;
  int nb = (N + SCAN_B - 1) / SCAN_B;
  degree_kernel<<<eb, 256, 0, stream>>>(dstv, deg, E);
  scan_partial_kernel<<<nb, SCAN_B, 0, stream>>>(deg, partial, N);
  scan_offsets_kernel<<<1, 256, 0, stream>>>(partial, nb);
  scan_final_kernel<<<nb, SCAN_B, 0, stream>>>(deg, partial, rowStart, N, E);
  fill_kernel<<<eb, 256, 0, stream>>>(srcv, dstv, rowStart, cursor, colv, E);

  // layer 1
  gemm1_kernel<<<(N + 7) / 8, 128, 0, stream>>>(x, W1, a_src1, a_dst1, h1, as1, ad1, N);
  gat_aggr3_kernel<128, 4><<<(N + 7) / 8, 256, 0, stream>>>(h1, as1, ad1, rowStart, colv, b1, act1, N);

  // layer 2
  gemm2_kernel<<<(N + 7) / 8, 128, 0, stream>>>(act1, W2, a_src2, a_dst2, h2, as2, ad2, N);
  gat_aggr3_kernel<32, 1><<<(N + 31) / 32, 256, 0, stream>>>(h2, as2, ad2, rowStart, colv, b2, act2, N);

  // pool + classify
  pool_kernel<<<(N + 63) / 64, 256, 0, stream>>>(act2, batch, pooled, cntG, N);
  classifier_kernel<<<(G + 255) / 256, 256, 0, stream>>>(pooled, cntG, Wc1, bc1, Wc2, bc2,
                                                         (float*)d_out, G);
}